// Round 10
// baseline (1744.293 us; speedup 1.0000x reference)
//
#include <hip/hip_runtime.h>

#define B_ 32
#define N_ 196
#define D_ 512
#define C_ 500
#define ND_ 51

typedef __attribute__((ext_vector_type(8))) short short8_t;
typedef __attribute__((ext_vector_type(4))) unsigned short us4_t;
typedef __attribute__((ext_vector_type(4))) float f32x4;

typedef const __attribute__((address_space(1))) unsigned int* gas_p;
typedef __attribute__((address_space(3))) unsigned int* las_p;
#define GLDS(gp, lp) __builtin_amdgcn_global_load_lds((gas_p)(gp), (las_p)(lp), 16, 0, 0)

__device__ inline unsigned short f2bf(float f) {
    unsigned u = __float_as_uint(f);
    u += 0x7FFFu + ((u >> 16) & 1u);   // RNE
    return (unsigned short)(u >> 16);
}

// ---------------- fp32 -> bf16 pre-convert (one-shot) ----------------
__global__ __launch_bounds__(256) void k_cvt(const float4* __restrict__ src,
                                             us4_t* __restrict__ dst, int n4) {
    const int i = blockIdx.x * 256 + threadIdx.x;
    if (i < n4) {
        float4 f = src[i];
        us4_t p = {f2bf(f.x), f2bf(f.y), f2bf(f.z), f2bf(f.w)};
        dst[i] = p;
    }
}

// ---------------- v[n,c] = softmax_n( mean[c,:] . text[n,c,:] ) ----------------
__global__ __launch_bounds__(256) void k_v(const float* __restrict__ mean,
                                           const float* __restrict__ text,
                                           float* __restrict__ vout) {
    const int c = blockIdx.x;
    const int w = threadIdx.x >> 6, lane = threadIdx.x & 63;
    __shared__ float sc[ND_];
    float md[8];
#pragma unroll
    for (int t = 0; t < 8; ++t) md[t] = mean[c * 512 + lane + 64 * t];
    for (int j = 0; j < 13; ++j) {
        const int n = w + 4 * j;
        if (n < ND_) {
            const float* tp = &text[((size_t)n * C_ + c) * 512];
            float a = 0.f;
#pragma unroll
            for (int t = 0; t < 8; ++t) a += md[t] * tp[lane + 64 * t];
#pragma unroll
            for (int off = 32; off; off >>= 1) a += __shfl_xor(a, off);
            if (lane == 0) sc[n] = a;
        }
    }
    __syncthreads();
    if (w == 0) {
        float xv = (lane < ND_) ? sc[lane] : -INFINITY;
        float mx = xv;
#pragma unroll
        for (int off = 32; off; off >>= 1) mx = fmaxf(mx, __shfl_xor(mx, off));
        float e = (lane < ND_) ? expf(xv - mx) : 0.f;
        float sum = e;
#pragma unroll
        for (int off = 32; off; off >>= 1) sum += __shfl_xor(sum, off);
        if (lane < ND_) vout[lane * C_ + c] = e / sum;
    }
}

// -------- s[b,m] = text[0,0,:].local[b,m,:]; wm[b,m] = image[b,:].local[b,m,:] --------
__global__ __launch_bounds__(256) void k_sw(const float* __restrict__ image,
                                            const float* __restrict__ localf,
                                            const float* __restrict__ text,
                                            float* __restrict__ s_ws,
                                            float* __restrict__ wm_ws) {
    const int b = blockIdx.x;
    const int m0 = blockIdx.y * 28;
    const int w = threadIdx.x >> 6, lane = threadIdx.x & 63;
    float t00[8], img[8];
#pragma unroll
    for (int t = 0; t < 8; ++t) {
        t00[t] = text[lane + 64 * t];
        img[t] = image[b * 512 + lane + 64 * t];
    }
    for (int t7 = 0; t7 < 7; ++t7) {
        const int m = m0 + w * 7 + t7;
        const float* lp = &localf[((size_t)b * N_ + m) * 512];
        float a = 0.f, g = 0.f;
#pragma unroll
        for (int t = 0; t < 8; ++t) {
            const float lv = lp[lane + 64 * t];
            a += t00[t] * lv;
            g += img[t] * lv;
        }
#pragma unroll
        for (int off = 32; off; off >>= 1) {
            a += __shfl_xor(a, off);
            g += __shfl_xor(g, off);
        }
        if (lane == 0) { s_ws[b * N_ + m] = a; wm_ws[b * N_ + m] = g; }
    }
}

// -------- wg[b,k] = softmax over top-50 (by s) of wm, in rank order --------
__global__ __launch_bounds__(64) void k_sel(const float* __restrict__ s_ws,
                                            const float* __restrict__ wm_ws,
                                            float* __restrict__ wgout) {
    const int b = blockIdx.x;
    const int lane = threadIdx.x;
    const unsigned long long ltmask = (1ull << lane) - 1ull;
    __shared__ float cv[64], cw[64];

    float x[4], p[4];
#pragma unroll
    for (int i = 0; i < 4; ++i) {
        const int m = lane + 64 * i;
        x[i] = (m < N_) ? s_ws[b * N_ + m] : -INFINITY;
        p[i] = (m < N_) ? wm_ws[b * N_ + m] : 0.f;
    }
    float lo = -1.02f, hi = 1.02f;
    int cl = N_;
    for (int it = 0; it < 24; ++it) {
        const float t = 0.5f * (lo + hi);
        int cnum = 0;
#pragma unroll
        for (int i = 0; i < 4; ++i) cnum += __popcll(__ballot(x[i] > t));
        if (cnum >= 50) { lo = t; cl = cnum; if (cnum <= 64) break; }
        else hi = t;
    }
    bool f[4];
    if (cl <= 64) {
#pragma unroll
        for (int i = 0; i < 4; ++i) f[i] = x[i] > lo;
    } else {
        int s1 = 0;
#pragma unroll
        for (int i = 0; i < 4; ++i) s1 += __popcll(__ballot(x[i] > hi));
        const int need = 64 - s1;
        int run = 0;
#pragma unroll
        for (int i = 0; i < 4; ++i) {
            const bool mid = (x[i] > lo) && !(x[i] > hi);
            const unsigned long long bm = __ballot(mid);
            const int pos = run + __popcll(bm & ltmask);
            f[i] = (x[i] > hi) || (mid && pos < need);
            run += __popcll(bm);
        }
    }
    int basep = 0;
#pragma unroll
    for (int i = 0; i < 4; ++i) {
        const unsigned long long bm = __ballot(f[i]);
        const int pos = basep + __popcll(bm & ltmask);
        if (f[i]) { cv[pos] = x[i]; cw[pos] = p[i]; }
        basep += __popcll(bm);
    }
    __builtin_amdgcn_s_waitcnt(0);
    float y = (lane < basep) ? cv[lane] : -INFINITY;
    float z = (lane < basep) ? cw[lane] : 0.f;
#pragma unroll
    for (int k = 2; k <= 64; k <<= 1) {
#pragma unroll
        for (int s2 = k >> 1; s2 > 0; s2 >>= 1) {
            const float py = __shfl_xor(y, s2);
            const float pz = __shfl_xor(z, s2);
            const bool keep_max = ((lane & k) == 0) == ((lane & s2) == 0);
            const bool take = keep_max ? (py > y) : (py < y);
            if (take) { y = py; z = pz; }
        }
    }
    float xv = (lane < 50) ? z : -INFINITY;
    float mx = xv;
#pragma unroll
    for (int off = 32; off; off >>= 1) mx = fmaxf(mx, __shfl_xor(mx, off));
    float e = (lane < 50) ? expf(xv - mx) : 0.f;
    float sum = e;
#pragma unroll
    for (int off = 32; off; off >>= 1) sum += __shfl_xor(sum, off);
    if (lane < 50) wgout[b * 50 + lane] = e / sum;
}

// ------------------------------- main fused kernel (bf16 inputs) -------------------------------
// block = (c,b). BK=32 slabs (stg = A 196x64B + B 51x64B = 15808 B, XOR-swizzled, GLDS w=16);
// S_T stored as bf16 [51][200] shorts = 20400 B. Union -> 20480 B LDS -> ~6 blocks/CU (24 waves).
// Selection: dual-column bisect+compact+bitonic (R9), candidates scratch = consumed bf16 row.
__global__ __launch_bounds__(256, 6) void k_main(const float* __restrict__ image,
                                                 const float* __restrict__ mean,
                                                 const unsigned short* __restrict__ localbf,
                                                 const unsigned short* __restrict__ textbf,
                                                 const float* __restrict__ vws,
                                                 const float* __restrict__ wgws,
                                                 float* __restrict__ out) {
    const int c = blockIdx.x;
    const int b = blockIdx.y;
    const int tid = threadIdx.x;
    const int w = tid >> 6;
    const int lane = tid & 63;
    const int quad = lane >> 4;
    const int l16 = lane & 15;

    __shared__ __align__(16) union SU {
        unsigned short stg[7904];       // A at short 0 (196x32), B at short 6272 (51x32)
        unsigned short ST[ND_ * 200];   // bf16 S_T, stride 200 shorts (400 B/row)
    } u;
    __shared__ float wavepart[4];

    float base_reg = 0.f;
    if (w == 0) {
        float s = 0.f;
#pragma unroll
        for (int t = 0; t < 8; ++t)
            s += image[b * 512 + lane + 64 * t] * mean[c * 512 + lane + 64 * t];
#pragma unroll
        for (int off = 32; off; off >>= 1) s += __shfl_xor(s, off);
        base_reg = s;
    }

    f32x4 acc[4][4];
    const f32x4 zv = {0.f, 0.f, 0.f, 0.f};
#pragma unroll
    for (int i = 0; i < 4; ++i)
#pragma unroll
        for (int j = 0; j < 4; ++j) acc[i][j] = zv;

    const unsigned short* abase = localbf + (size_t)(b * N_) * 512;

    for (int ks = 0; ks < 16; ++ks) {
        // A: 196 rows x 4 chunks = 784 slots of 16 B; swizzle on the GLOBAL chunk index
#pragma unroll
        for (int i = 0; i < 4; ++i) {
            const int s = (i * 4 + w) * 64 + lane;
            if (s < 784) {
                const int r = s >> 2;
                const int cg = (s & 3) ^ (r & 3);
                GLDS(abase + (size_t)r * 512 + ks * 32 + cg * 8, (char*)u.stg + s * 16);
            }
        }
        // B: 51 rows x 4 chunks = 204 slots at byte 12544
        {
            const int s = w * 64 + lane;
            if (s < 204) {
                const int r = s >> 2;
                const int cg = (s & 3) ^ (r & 3);
                GLDS(textbf + (size_t)(r * C_ + c) * 512 + ks * 32 + cg * 8,
                     (char*)u.stg + 12544 + s * 16);
            }
        }
        __syncthreads();
        short8_t bfr[4];
#pragma unroll
        for (int nt = 0; nt < 4; ++nt) {
            const int row = nt * 16 + l16;
            bfr[nt] = *(const short8_t*)&u.stg[6272 + row * 32 + ((quad ^ (row & 3)) * 8)];
        }
#pragma unroll
        for (int mi = 0; mi < 4; ++mi) {
            const int mt = w + 4 * mi;
            if (mt < 13) {
                const int row = mt * 16 + l16;
                short8_t af = *(const short8_t*)&u.stg[row * 32 + ((quad ^ (row & 3)) * 8)];
#pragma unroll
                for (int nt = 0; nt < 4; ++nt)
                    acc[mi][nt] = __builtin_amdgcn_mfma_f32_16x16x32_bf16(af, bfr[nt], acc[mi][nt], 0, 0, 0);
            }
        }
        __syncthreads();
    }

    // S_T[n][m] as bf16, stride 200 shorts — GUARDED to n < ND_ AND m < 196
#pragma unroll
    for (int nt = 0; nt < 4; ++nt) {
        const int n = nt * 16 + l16;
        if (n < ND_) {
#pragma unroll
            for (int mi = 0; mi < 4; ++mi) {
                const int mt = w + 4 * mi;
                if (mt < 12 || (mt == 12 && quad == 0)) {
                    us4_t pk = {f2bf(acc[mi][nt][0]), f2bf(acc[mi][nt][1]),
                                f2bf(acc[mi][nt][2]), f2bf(acc[mi][nt][3])};
                    *(us4_t*)&u.ST[n * 200 + mt * 16 + quad * 4] = pk;
                }
            }
        }
    }
    __syncthreads();

    // -------- per-column top-50: TWO columns in lockstep (bisect -> compact -> bitonic) --------
    const float wgv = (lane < 50) ? wgws[b * 50 + lane] : 0.f;
    const unsigned long long ltmask = (1ull << lane) - 1ull;
    float waveacc = 0.f;

    for (int t = 0; t < 7; ++t) {
        const int n1 = w + 8 * t;
        const int n2 = n1 + 4;
        const bool a2 = (n2 < ND_);
        if (n1 >= ND_) break;
        unsigned short* row1 = &u.ST[n1 * 200];
        unsigned short* row2 = &u.ST[(a2 ? n2 : n1) * 200];  // alias (no writes) if inactive

        float x1[4], x2[4];
        if (lane < 49) {
            us4_t p1 = *(const us4_t*)&row1[lane * 4];
            us4_t p2 = *(const us4_t*)&row2[lane * 4];
#pragma unroll
            for (int r = 0; r < 4; ++r) {
                x1[r] = __uint_as_float(((unsigned)p1[r]) << 16);
                x2[r] = a2 ? __uint_as_float(((unsigned)p2[r]) << 16) : -INFINITY;
            }
        } else {
#pragma unroll
            for (int r = 0; r < 4; ++r) { x1[r] = -INFINITY; x2[r] = -INFINITY; }
        }

        // fused bisection
        float lo1 = -1.02f, hi1 = 1.02f, lo2 = -1.02f, hi2 = 1.02f;
        int cl1 = 256, cl2 = a2 ? 256 : 0;
        bool d1 = false, d2 = !a2;
        for (int it = 0; it < 24 && !(d1 && d2); ++it) {
            const float t1 = 0.5f * (lo1 + hi1);
            const float t2 = 0.5f * (lo2 + hi2);
            int c1 = 0, c2 = 0;
#pragma unroll
            for (int i = 0; i < 4; ++i) {
                c1 += __popcll(__ballot(x1[i] > t1));
                c2 += __popcll(__ballot(x2[i] > t2));
            }
            if (!d1) { if (c1 >= 50) { lo1 = t1; cl1 = c1; d1 = (c1 <= 64); } else hi1 = t1; }
            if (!d2) { if (c2 >= 50) { lo2 = t2; cl2 = c2; d2 = (c2 <= 64); } else hi2 = t2; }
        }

        bool f1[4], f2[4];
        int cnt1, cnt2;
        if (cl1 <= 64) {
#pragma unroll
            for (int i = 0; i < 4; ++i) f1[i] = x1[i] > lo1;
            cnt1 = cl1;
        } else {
            int s1 = 0;
#pragma unroll
            for (int i = 0; i < 4; ++i) s1 += __popcll(__ballot(x1[i] > hi1));
            const int need = 64 - s1;
            int run = 0;
#pragma unroll
            for (int i = 0; i < 4; ++i) {
                const bool mid = (x1[i] > lo1) && !(x1[i] > hi1);
                const unsigned long long bm = __ballot(mid);
                const int pos = run + __popcll(bm & ltmask);
                f1[i] = (x1[i] > hi1) || (mid && pos < need);
                run += __popcll(bm);
            }
            cnt1 = 64;
        }
        if (cl2 <= 64) {
#pragma unroll
            for (int i = 0; i < 4; ++i) f2[i] = x2[i] > lo2;
            cnt2 = cl2;
        } else {
            int s1 = 0;
#pragma unroll
            for (int i = 0; i < 4; ++i) s1 += __popcll(__ballot(x2[i] > hi2));
            const int need = 64 - s1;
            int run = 0;
#pragma unroll
            for (int i = 0; i < 4; ++i) {
                const bool mid = (x2[i] > lo2) && !(x2[i] > hi2);
                const unsigned long long bm = __ballot(mid);
                const int pos = run + __popcll(bm & ltmask);
                f2[i] = (x2[i] > hi2) || (mid && pos < need);
                run += __popcll(bm);
            }
            cnt2 = 64;
        }

        // fused compaction into each row's (already consumed) bytes, as f32 scratch
        float* rf1 = (float*)row1;
        float* rf2 = (float*)row2;
        int bp1 = 0, bp2 = 0;
#pragma unroll
        for (int i = 0; i < 4; ++i) {
            const unsigned long long bm1 = __ballot(f1[i]);
            const unsigned long long bm2 = __ballot(f2[i]);
            const int p1 = bp1 + __popcll(bm1 & ltmask);
            const int p2 = bp2 + __popcll(bm2 & ltmask);
            if (f1[i]) rf1[p1] = x1[i];
            if (f2[i]) rf2[p2] = x2[i];
            bp1 += __popcll(bm1);
            bp2 += __popcll(bm2);
        }
        __builtin_amdgcn_s_waitcnt(0);
        float y1 = (lane < cnt1) ? rf1[lane] : -INFINITY;
        float y2 = (lane < cnt2) ? rf2[lane] : -INFINITY;

        // fused bitonic sort 64, descending
#pragma unroll
        for (int k = 2; k <= 64; k <<= 1) {
#pragma unroll
            for (int s2 = k >> 1; s2 > 0; s2 >>= 1) {
                const bool up = ((lane & k) == 0) == ((lane & s2) == 0);
                const float p1 = __shfl_xor(y1, s2);
                const float p2 = __shfl_xor(y2, s2);
                y1 = up ? fmaxf(y1, p1) : fminf(y1, p1);
                y2 = up ? fmaxf(y2, p2) : fminf(y2, p2);
            }
        }
        float part1 = (lane < 50) ? y1 * wgv : 0.f;
        float part2 = (lane < 50) ? y2 * wgv : 0.f;
#pragma unroll
        for (int off = 32; off; off >>= 1) {
            part1 += __shfl_xor(part1, off);
            part2 += __shfl_xor(part2, off);
        }
        waveacc += vws[n1 * C_ + c] * part1;
        if (a2) waveacc += vws[n2 * C_ + c] * part2;
    }

    if (lane == 0) wavepart[w] = waveacc;
    __syncthreads();
    if (tid == 0)
        out[b * C_ + c] = base_reg + wavepart[0] + wavepart[1] + wavepart[2] + wavepart[3];
}

// --------------- fallback main kernel (fp32 inputs, in-kernel cvt; proven) ---------------
__global__ __launch_bounds__(256) void k_main_fb(const float* __restrict__ image,
                                                 const float* __restrict__ localf,
                                                 const float* __restrict__ text,
                                                 const float* __restrict__ mean,
                                                 const float* __restrict__ vws,
                                                 const float* __restrict__ wgws,
                                                 float* __restrict__ out) {
    const int c = blockIdx.x;
    const int b = blockIdx.y;
    const int tid = threadIdx.x;
    const int w = tid >> 6;
    const int lane = tid & 63;
    const int quad = lane >> 4;
    const int l16 = lane & 15;

    __shared__ __align__(16) union SU {
        struct { unsigned short A[208 * 72]; unsigned short Bm[64 * 72]; } st;
        float S[208 * 65];
    } u;
    __shared__ float wavepart[4];
    __shared__ float basev;

    if (w == 0) {
        float s = 0.f;
#pragma unroll
        for (int t = 0; t < 8; ++t)
            s += image[b * 512 + lane + 64 * t] * mean[c * 512 + lane + 64 * t];
#pragma unroll
        for (int off = 32; off; off >>= 1) s += __shfl_xor(s, off);
        if (lane == 0) basev = s;
    }

    f32x4 acc[4][4];
    const f32x4 zv = {0.f, 0.f, 0.f, 0.f};
#pragma unroll
    for (int i = 0; i < 4; ++i)
#pragma unroll
        for (int j = 0; j < 4; ++j) acc[i][j] = zv;

    const int lbase = (b * N_) * 512;
    for (int ks = 0; ks < 8; ++ks) {
        const int k0 = ks * 64;
        for (int e = tid; e < 3328; e += 256) {
            const int m = e >> 4, kc4 = e & 15;
            float4 fv = make_float4(0.f, 0.f, 0.f, 0.f);
            if (m < N_) fv = *(const float4*)&localf[lbase + m * 512 + k0 + kc4 * 4];
            us4_t pk = {f2bf(fv.x), f2bf(fv.y), f2bf(fv.z), f2bf(fv.w)};
            *(us4_t*)&u.st.A[m * 72 + kc4 * 4] = pk;
        }
        for (int e = tid; e < 1024; e += 256) {
            const int n = e >> 4, kc4 = e & 15;
            float4 fv = make_float4(0.f, 0.f, 0.f, 0.f);
            if (n < ND_) fv = *(const float4*)&text[((size_t)n * C_ + c) * 512 + k0 + kc4 * 4];
            us4_t pk = {f2bf(fv.x), f2bf(fv.y), f2bf(fv.z), f2bf(fv.w)};
            *(us4_t*)&u.st.Bm[n * 72 + kc4 * 4] = pk;
        }
        __syncthreads();
#pragma unroll
        for (int kc = 0; kc < 2; ++kc) {
            short8_t bfr[4];
#pragma unroll
            for (int nt = 0; nt < 4; ++nt)
                bfr[nt] = *(const short8_t*)&u.st.Bm[(nt * 16 + l16) * 72 + kc * 32 + quad * 8];
#pragma unroll
            for (int mi = 0; mi < 4; ++mi) {
                const int mt = w + 4 * mi;
                if (mt < 13) {
                    short8_t af = *(const short8_t*)&u.st.A[(mt * 16 + l16) * 72 + kc * 32 + quad * 8];
#pragma unroll
                    for (int nt = 0; nt < 4; ++nt)
                        acc[mi][nt] = __builtin_amdgcn_mfma_f32_16x16x32_bf16(af, bfr[nt], acc[mi][nt], 0, 0, 0);
                }
            }
        }
        __syncthreads();
    }

#pragma unroll
    for (int mi = 0; mi < 4; ++mi) {
        const int mt = w + 4 * mi;
        if (mt < 13) {
#pragma unroll
            for (int nt = 0; nt < 4; ++nt)
#pragma unroll
                for (int r = 0; r < 4; ++r)
                    u.S[(mt * 16 + quad * 4 + r) * 65 + nt * 16 + l16] = acc[mi][nt][r];
        }
    }
    __syncthreads();

    const float wgv = (lane < 50) ? wgws[b * 50 + lane] : 0.f;
    float waveacc = 0.f;

    for (int j = 0; j < 13; ++j) {
        const int n = w + 4 * j;
        if (n < ND_) {
            float x[4];
#pragma unroll
            for (int i = 0; i < 4; ++i) {
                const int m = lane + 64 * i;
                x[i] = (m < N_) ? u.S[m * 65 + n] : -INFINITY;
            }
#pragma unroll
            for (int k = 2; k <= 64; k <<= 1) {
#pragma unroll
                for (int s2 = k >> 1; s2 > 0; s2 >>= 1) {
                    const bool up = ((lane & k) == 0) == ((lane & s2) == 0);
#pragma unroll
                    for (int r = 0; r < 4; ++r) {
                        const float p = __shfl_xor(x[r], s2);
                        x[r] = up ? fmaxf(x[r], p) : fminf(x[r], p);
                    }
                }
            }
            float m01 = fmaxf(x[0], __shfl_xor(x[1], 63));
            float m23 = fmaxf(x[2], __shfl_xor(x[3], 63));
#pragma unroll
            for (int s2 = 32; s2 > 0; s2 >>= 1) {
                const bool up = (lane & s2) == 0;
                const float p0 = __shfl_xor(m01, s2);
                const float p1 = __shfl_xor(m23, s2);
                m01 = up ? fmaxf(m01, p0) : fminf(m01, p0);
                m23 = up ? fmaxf(m23, p1) : fminf(m23, p1);
            }
            float y = fmaxf(m01, __shfl_xor(m23, 63));
#pragma unroll
            for (int s2 = 32; s2 > 0; s2 >>= 1) {
                const bool up = (lane & s2) == 0;
                const float p = __shfl_xor(y, s2);
                y = up ? fmaxf(y, p) : fminf(y, p);
            }
            float part = (lane < 50) ? y * wgv : 0.f;
#pragma unroll
            for (int off = 32; off; off >>= 1) part += __shfl_xor(part, off);
            waveacc += vws[n * C_ + c] * part;
        }
    }

    if (lane == 0) wavepart[w] = waveacc;
    __syncthreads();
    if (tid == 0)
        out[b * C_ + c] = basev + wavepart[0] + wavepart[1] + wavepart[2] + wavepart[3];
}

extern "C" void kernel_launch(void* const* d_in, const int* in_sizes, int n_in,
                              void* d_out, int out_size, void* d_ws, size_t ws_size,
                              hipStream_t stream) {
    (void)in_sizes; (void)n_in; (void)out_size;
    const float* image = (const float*)d_in[0];
    const float* localf = (const float*)d_in[1];
    const float* text  = (const float*)d_in[2];
    const float* mean  = (const float*)d_in[3];
    float* out = (float*)d_out;

    float* vws   = (float*)d_ws;            // 25500
    float* wgws  = vws + ND_ * C_;          // 1600
    float* s_ws  = wgws + B_ * 50;          // 6272
    float* wm_ws = s_ws + B_ * N_;          // 6272
    const size_t small_bytes = (size_t)(ND_ * C_ + B_ * 50 + 2 * B_ * N_) * 4;
    const size_t bf_bytes = ((size_t)B_ * N_ * D_ + (size_t)ND_ * C_ * D_) * 2;

    hipLaunchKernelGGL(k_v, dim3(C_), dim3(256), 0, stream, mean, text, vws);
    hipLaunchKernelGGL(k_sw, dim3(B_, 7), dim3(256), 0, stream, image, localf, text, s_ws, wm_ws);
    hipLaunchKernelGGL(k_sel, dim3(B_), dim3(64), 0, stream, s_ws, wm_ws, wgws);

    if (ws_size >= small_bytes + bf_bytes) {
        unsigned short* localbf = (unsigned short*)(wm_ws + B_ * N_);
        unsigned short* textbf  = localbf + (size_t)B_ * N_ * D_;
        const int n4_local = B_ * N_ * D_ / 4;
        const int n4_text  = ND_ * C_ * D_ / 4;
        hipLaunchKernelGGL(k_cvt, dim3((n4_local + 255) / 256), dim3(256), 0, stream,
                           (const float4*)localf, (us4_t*)localbf, n4_local);
        hipLaunchKernelGGL(k_cvt, dim3((n4_text + 255) / 256), dim3(256), 0, stream,
                           (const float4*)text, (us4_t*)textbf, n4_text);
        hipLaunchKernelGGL(k_main, dim3(C_, B_), dim3(256), 0, stream,
                           image, mean, localbf, textbf, vws, wgws, out);
    } else {
        hipLaunchKernelGGL(k_main_fb, dim3(C_, B_), dim3(256), 0, stream,
                           image, localf, text, mean, vws, wgws, out);
    }
}

// Round 11
// 741.168 us; speedup vs baseline: 2.3534x; 2.3534x over previous
//
#include <hip/hip_runtime.h>

#define B_ 32
#define N_ 196
#define D_ 512
#define C_ 500
#define ND_ 51

typedef __attribute__((ext_vector_type(8))) short short8_t;
typedef __attribute__((ext_vector_type(4))) unsigned short us4_t;
typedef __attribute__((ext_vector_type(4))) float f32x4;

typedef const __attribute__((address_space(1))) unsigned int* gas_p;
typedef __attribute__((address_space(3))) unsigned int* las_p;
#define GLDS(gp, lp) __builtin_amdgcn_global_load_lds((gas_p)(gp), (las_p)(lp), 16, 0, 0)

__device__ inline unsigned short f2bf(float f) {
    unsigned u = __float_as_uint(f);
    u += 0x7FFFu + ((u >> 16) & 1u);   // RNE
    return (unsigned short)(u >> 16);
}

// ---------------- fp32 -> bf16 pre-convert (one-shot) ----------------
__global__ __launch_bounds__(256) void k_cvt(const float4* __restrict__ src,
                                             us4_t* __restrict__ dst, int n4) {
    const int i = blockIdx.x * 256 + threadIdx.x;
    if (i < n4) {
        float4 f = src[i];
        us4_t p = {f2bf(f.x), f2bf(f.y), f2bf(f.z), f2bf(f.w)};
        dst[i] = p;
    }
}

// ---------------- v[n,c] = softmax_n( mean[c,:] . text[n,c,:] ) ----------------
__global__ __launch_bounds__(256) void k_v(const float* __restrict__ mean,
                                           const float* __restrict__ text,
                                           float* __restrict__ vout) {
    const int c = blockIdx.x;
    const int w = threadIdx.x >> 6, lane = threadIdx.x & 63;
    __shared__ float sc[ND_];
    float md[8];
#pragma unroll
    for (int t = 0; t < 8; ++t) md[t] = mean[c * 512 + lane + 64 * t];
    for (int j = 0; j < 13; ++j) {
        const int n = w + 4 * j;
        if (n < ND_) {
            const float* tp = &text[((size_t)n * C_ + c) * 512];
            float a = 0.f;
#pragma unroll
            for (int t = 0; t < 8; ++t) a += md[t] * tp[lane + 64 * t];
#pragma unroll
            for (int off = 32; off; off >>= 1) a += __shfl_xor(a, off);
            if (lane == 0) sc[n] = a;
        }
    }
    __syncthreads();
    if (w == 0) {
        float xv = (lane < ND_) ? sc[lane] : -INFINITY;
        float mx = xv;
#pragma unroll
        for (int off = 32; off; off >>= 1) mx = fmaxf(mx, __shfl_xor(mx, off));
        float e = (lane < ND_) ? expf(xv - mx) : 0.f;
        float sum = e;
#pragma unroll
        for (int off = 32; off; off >>= 1) sum += __shfl_xor(sum, off);
        if (lane < ND_) vout[lane * C_ + c] = e / sum;
    }
}

// -------- s[b,m] = text[0,0,:].local[b,m,:]; wm[b,m] = image[b,:].local[b,m,:] --------
__global__ __launch_bounds__(256) void k_sw(const float* __restrict__ image,
                                            const float* __restrict__ localf,
                                            const float* __restrict__ text,
                                            float* __restrict__ s_ws,
                                            float* __restrict__ wm_ws) {
    const int b = blockIdx.x;
    const int m0 = blockIdx.y * 28;
    const int w = threadIdx.x >> 6, lane = threadIdx.x & 63;
    float t00[8], img[8];
#pragma unroll
    for (int t = 0; t < 8; ++t) {
        t00[t] = text[lane + 64 * t];
        img[t] = image[b * 512 + lane + 64 * t];
    }
    for (int t7 = 0; t7 < 7; ++t7) {
        const int m = m0 + w * 7 + t7;
        const float* lp = &localf[((size_t)b * N_ + m) * 512];
        float a = 0.f, g = 0.f;
#pragma unroll
        for (int t = 0; t < 8; ++t) {
            const float lv = lp[lane + 64 * t];
            a += t00[t] * lv;
            g += img[t] * lv;
        }
#pragma unroll
        for (int off = 32; off; off >>= 1) {
            a += __shfl_xor(a, off);
            g += __shfl_xor(g, off);
        }
        if (lane == 0) { s_ws[b * N_ + m] = a; wm_ws[b * N_ + m] = g; }
    }
}

// -------- wg[b,k] = softmax over top-50 (by s) of wm, in rank order --------
__global__ __launch_bounds__(64) void k_sel(const float* __restrict__ s_ws,
                                            const float* __restrict__ wm_ws,
                                            float* __restrict__ wgout) {
    const int b = blockIdx.x;
    const int lane = threadIdx.x;
    const unsigned long long ltmask = (1ull << lane) - 1ull;
    __shared__ float cv[64], cw[64];

    float x[4], p[4];
#pragma unroll
    for (int i = 0; i < 4; ++i) {
        const int m = lane + 64 * i;
        x[i] = (m < N_) ? s_ws[b * N_ + m] : -INFINITY;
        p[i] = (m < N_) ? wm_ws[b * N_ + m] : 0.f;
    }
    float lo = -1.02f, hi = 1.02f;
    int cl = N_;
    for (int it = 0; it < 24; ++it) {
        const float t = 0.5f * (lo + hi);
        int cnum = 0;
#pragma unroll
        for (int i = 0; i < 4; ++i) cnum += __popcll(__ballot(x[i] > t));
        if (cnum >= 50) { lo = t; cl = cnum; if (cnum <= 64) break; }
        else hi = t;
    }
    bool f[4];
    if (cl <= 64) {
#pragma unroll
        for (int i = 0; i < 4; ++i) f[i] = x[i] > lo;
    } else {
        int s1 = 0;
#pragma unroll
        for (int i = 0; i < 4; ++i) s1 += __popcll(__ballot(x[i] > hi));
        const int need = 64 - s1;
        int run = 0;
#pragma unroll
        for (int i = 0; i < 4; ++i) {
            const bool mid = (x[i] > lo) && !(x[i] > hi);
            const unsigned long long bm = __ballot(mid);
            const int pos = run + __popcll(bm & ltmask);
            f[i] = (x[i] > hi) || (mid && pos < need);
            run += __popcll(bm);
        }
    }
    int basep = 0;
#pragma unroll
    for (int i = 0; i < 4; ++i) {
        const unsigned long long bm = __ballot(f[i]);
        const int pos = basep + __popcll(bm & ltmask);
        if (f[i]) { cv[pos] = x[i]; cw[pos] = p[i]; }
        basep += __popcll(bm);
    }
    __builtin_amdgcn_s_waitcnt(0);
    float y = (lane < basep) ? cv[lane] : -INFINITY;
    float z = (lane < basep) ? cw[lane] : 0.f;
#pragma unroll
    for (int k = 2; k <= 64; k <<= 1) {
#pragma unroll
        for (int s2 = k >> 1; s2 > 0; s2 >>= 1) {
            const float py = __shfl_xor(y, s2);
            const float pz = __shfl_xor(z, s2);
            const bool keep_max = ((lane & k) == 0) == ((lane & s2) == 0);
            const bool take = keep_max ? (py > y) : (py < y);
            if (take) { y = py; z = pz; }
        }
    }
    float xv = (lane < 50) ? z : -INFINITY;
    float mx = xv;
#pragma unroll
    for (int off = 32; off; off >>= 1) mx = fmaxf(mx, __shfl_xor(mx, off));
    float e = (lane < 50) ? expf(xv - mx) : 0.f;
    float sum = e;
#pragma unroll
    for (int off = 32; off; off >>= 1) sum += __shfl_xor(sum, off);
    if (lane < 50) wgout[b * 50 + lane] = e / sum;
}

// ------------------------------- main fused kernel (bf16 inputs) -------------------------------
// block = (c,b), 512 threads / 8 waves. acc[2][4] = 32 regs/wave (vs 64 at 4 waves) -> fits
// 6 waves/SIMD reg budget (85) -> 3 blocks/CU = 24 waves (75% occ). GLDS w=16 staging,
// LDS union( stg 34816 B, ST[51][200] f32 40800 B ) = 40960 B. Dual-column bisect+compact+bitonic.
__global__ __launch_bounds__(512, 6) void k_main(const float* __restrict__ image,
                                                 const float* __restrict__ mean,
                                                 const unsigned short* __restrict__ localbf,
                                                 const unsigned short* __restrict__ textbf,
                                                 const float* __restrict__ vws,
                                                 const float* __restrict__ wgws,
                                                 float* __restrict__ out) {
    const int c = blockIdx.x;
    const int b = blockIdx.y;
    const int tid = threadIdx.x;
    const int w = tid >> 6;          // 0..7
    const int lane = tid & 63;
    const int quad = lane >> 4;
    const int l16 = lane & 15;

    __shared__ __align__(16) union SU {
        unsigned short stg[208 * 64 + 64 * 64];  // A at short 0, B at short 13312 (byte 26624)
        float ST[ND_ * 200];                     // stride 200; col 196 = wave partials (rows 0..7)
    } u;

    float base_reg = 0.f;
    if (w == 0) {
        float s = 0.f;
#pragma unroll
        for (int t = 0; t < 8; ++t)
            s += image[b * 512 + lane + 64 * t] * mean[c * 512 + lane + 64 * t];
#pragma unroll
        for (int off = 32; off; off >>= 1) s += __shfl_xor(s, off);
        base_reg = s;
    }

    f32x4 acc[2][4];
    const f32x4 zv = {0.f, 0.f, 0.f, 0.f};
#pragma unroll
    for (int i = 0; i < 2; ++i)
#pragma unroll
        for (int j = 0; j < 4; ++j) acc[i][j] = zv;

    const unsigned short* abase = localbf + (size_t)(b * N_) * 512;

    for (int ks = 0; ks < 8; ++ks) {
        // A: 1568 16B slots over 512 threads (tail-masked waves keep lane 0 active)
#pragma unroll
        for (int i = 0; i < 4; ++i) {
            const int s = i * 512 + tid;
            if (s < 1568) {
                const int r = s >> 3;
                const int c8 = (s & 7) ^ (r & 7);
                GLDS(abase + (size_t)r * 512 + ks * 64 + c8 * 8, (char*)u.stg + s * 16);
            }
        }
        // B: 408 slots at byte 26624 (single pass of 512 threads)
        {
            const int s = tid;
            if (s < 408) {
                const int r = s >> 3;
                const int c8 = (s & 7) ^ (r & 7);
                GLDS(textbf + (size_t)(r * C_ + c) * 512 + ks * 64 + c8 * 8,
                     (char*)u.stg + 26624 + s * 16);
            }
        }
        __syncthreads();
#pragma unroll
        for (int kc = 0; kc < 2; ++kc) {
            short8_t bfr[4];
#pragma unroll
            for (int nt = 0; nt < 4; ++nt) {
                const int row = nt * 16 + l16;
                const int j = kc * 4 + quad;
                bfr[nt] = *(const short8_t*)&u.stg[13312 + row * 64 + ((j ^ (row & 7)) * 8)];
            }
#pragma unroll
            for (int mi = 0; mi < 2; ++mi) {
                const int mt = w + 8 * mi;
                if (mt < 13) {
                    const int row = mt * 16 + l16;
                    const int j = kc * 4 + quad;
                    short8_t af = *(const short8_t*)&u.stg[row * 64 + ((j ^ (row & 7)) * 8)];
#pragma unroll
                    for (int nt = 0; nt < 4; ++nt)
                        acc[mi][nt] = __builtin_amdgcn_mfma_f32_16x16x32_bf16(af, bfr[nt], acc[mi][nt], 0, 0, 0);
                }
            }
        }
        __syncthreads();
    }

    // S_T[n][m], stride 200 floats — GUARDED to n < ND_ AND m < 196
#pragma unroll
    for (int nt = 0; nt < 4; ++nt) {
        const int n = nt * 16 + l16;
        if (n < ND_) {
#pragma unroll
            for (int mi = 0; mi < 2; ++mi) {
                const int mt = w + 8 * mi;
                if (mt < 12 || (mt == 12 && quad == 0))
                    *(f32x4*)&u.ST[n * 200 + mt * 16 + quad * 4] = acc[mi][nt];
            }
        }
    }
    __syncthreads();

    // -------- per-column top-50: TWO columns in lockstep; wave w owns n ≡ w (mod 8) --------
    const float wgv = (lane < 50) ? wgws[b * 50 + lane] : 0.f;
    const unsigned long long ltmask = (1ull << lane) - 1ull;
    float waveacc = 0.f;

    for (int t = 0; t < 4; ++t) {
        const int n1 = w + 16 * t;
        const int n2 = n1 + 8;
        const bool a2 = (n2 < ND_);
        if (n1 >= ND_) break;
        float* rowp1 = &u.ST[n1 * 200];
        float* rowp2 = &u.ST[(a2 ? n2 : n1) * 200];  // alias (reads only) if col2 inactive

        float x1[4], x2[4];
        if (lane < 49) {
            f32x4 v1 = *(const f32x4*)&rowp1[lane * 4];
            f32x4 v2 = *(const f32x4*)&rowp2[lane * 4];
#pragma unroll
            for (int r = 0; r < 4; ++r) { x1[r] = v1[r]; x2[r] = a2 ? v2[r] : -INFINITY; }
        } else {
#pragma unroll
            for (int r = 0; r < 4; ++r) { x1[r] = -INFINITY; x2[r] = -INFINITY; }
        }

        float lo1 = -1.02f, hi1 = 1.02f, lo2 = -1.02f, hi2 = 1.02f;
        int cl1 = 256, cl2 = a2 ? 256 : 0;
        bool d1 = false, d2 = !a2;
        for (int it = 0; it < 24 && !(d1 && d2); ++it) {
            const float t1 = 0.5f * (lo1 + hi1);
            const float t2 = 0.5f * (lo2 + hi2);
            int c1 = 0, c2 = 0;
#pragma unroll
            for (int i = 0; i < 4; ++i) {
                c1 += __popcll(__ballot(x1[i] > t1));
                c2 += __popcll(__ballot(x2[i] > t2));
            }
            if (!d1) { if (c1 >= 50) { lo1 = t1; cl1 = c1; d1 = (c1 <= 64); } else hi1 = t1; }
            if (!d2) { if (c2 >= 50) { lo2 = t2; cl2 = c2; d2 = (c2 <= 64); } else hi2 = t2; }
        }

        bool f1[4], f2[4];
        int cnt1, cnt2;
        if (cl1 <= 64) {
#pragma unroll
            for (int i = 0; i < 4; ++i) f1[i] = x1[i] > lo1;
            cnt1 = cl1;
        } else {
            int s1 = 0;
#pragma unroll
            for (int i = 0; i < 4; ++i) s1 += __popcll(__ballot(x1[i] > hi1));
            const int need = 64 - s1;
            int run = 0;
#pragma unroll
            for (int i = 0; i < 4; ++i) {
                const bool mid = (x1[i] > lo1) && !(x1[i] > hi1);
                const unsigned long long bm = __ballot(mid);
                const int pos = run + __popcll(bm & ltmask);
                f1[i] = (x1[i] > hi1) || (mid && pos < need);
                run += __popcll(bm);
            }
            cnt1 = 64;
        }
        if (cl2 <= 64) {
#pragma unroll
            for (int i = 0; i < 4; ++i) f2[i] = x2[i] > lo2;
            cnt2 = cl2;
        } else {
            int s1 = 0;
#pragma unroll
            for (int i = 0; i < 4; ++i) s1 += __popcll(__ballot(x2[i] > hi2));
            const int need = 64 - s1;
            int run = 0;
#pragma unroll
            for (int i = 0; i < 4; ++i) {
                const bool mid = (x2[i] > lo2) && !(x2[i] > hi2);
                const unsigned long long bm = __ballot(mid);
                const int pos = run + __popcll(bm & ltmask);
                f2[i] = (x2[i] > hi2) || (mid && pos < need);
                run += __popcll(bm);
            }
            cnt2 = 64;
        }

        int bp1 = 0, bp2 = 0;
#pragma unroll
        for (int i = 0; i < 4; ++i) {
            const unsigned long long bm1 = __ballot(f1[i]);
            const unsigned long long bm2 = __ballot(f2[i]);
            const int p1 = bp1 + __popcll(bm1 & ltmask);
            const int p2 = bp2 + __popcll(bm2 & ltmask);
            if (f1[i]) rowp1[p1] = x1[i];
            if (f2[i]) rowp2[p2] = x2[i];
            bp1 += __popcll(bm1);
            bp2 += __popcll(bm2);
        }
        __builtin_amdgcn_s_waitcnt(0);
        float y1 = (lane < cnt1) ? rowp1[lane] : -INFINITY;
        float y2 = (lane < cnt2) ? rowp2[lane] : -INFINITY;

#pragma unroll
        for (int k = 2; k <= 64; k <<= 1) {
#pragma unroll
            for (int s2 = k >> 1; s2 > 0; s2 >>= 1) {
                const bool up = ((lane & k) == 0) == ((lane & s2) == 0);
                const float p1 = __shfl_xor(y1, s2);
                const float p2 = __shfl_xor(y2, s2);
                y1 = up ? fmaxf(y1, p1) : fminf(y1, p1);
                y2 = up ? fmaxf(y2, p2) : fminf(y2, p2);
            }
        }
        float part1 = (lane < 50) ? y1 * wgv : 0.f;
        float part2 = (lane < 50) ? y2 * wgv : 0.f;
#pragma unroll
        for (int off = 32; off; off >>= 1) {
            part1 += __shfl_xor(part1, off);
            part2 += __shfl_xor(part2, off);
        }
        waveacc += vws[n1 * C_ + c] * part1;
        if (a2) waveacc += vws[n2 * C_ + c] * part2;
    }

    // wave partial -> col 196 of row w (row w's scratch belongs to this wave, already done)
    if (lane == 0) u.ST[w * 200 + 196] = waveacc;
    __syncthreads();
    if (tid == 0) {
        float r = base_reg;
#pragma unroll
        for (int i = 0; i < 8; ++i) r += u.ST[i * 200 + 196];
        out[b * C_ + c] = r;
    }
}

// --------------- fallback main kernel (fp32 inputs, in-kernel cvt; proven) ---------------
__global__ __launch_bounds__(256) void k_main_fb(const float* __restrict__ image,
                                                 const float* __restrict__ localf,
                                                 const float* __restrict__ text,
                                                 const float* __restrict__ mean,
                                                 const float* __restrict__ vws,
                                                 const float* __restrict__ wgws,
                                                 float* __restrict__ out) {
    const int c = blockIdx.x;
    const int b = blockIdx.y;
    const int tid = threadIdx.x;
    const int w = tid >> 6;
    const int lane = tid & 63;
    const int quad = lane >> 4;
    const int l16 = lane & 15;

    __shared__ __align__(16) union SU {
        struct { unsigned short A[208 * 72]; unsigned short Bm[64 * 72]; } st;
        float S[208 * 65];
    } u;
    __shared__ float wavepart[4];
    __shared__ float basev;

    if (w == 0) {
        float s = 0.f;
#pragma unroll
        for (int t = 0; t < 8; ++t)
            s += image[b * 512 + lane + 64 * t] * mean[c * 512 + lane + 64 * t];
#pragma unroll
        for (int off = 32; off; off >>= 1) s += __shfl_xor(s, off);
        if (lane == 0) basev = s;
    }

    f32x4 acc[4][4];
    const f32x4 zv = {0.f, 0.f, 0.f, 0.f};
#pragma unroll
    for (int i = 0; i < 4; ++i)
#pragma unroll
        for (int j = 0; j < 4; ++j) acc[i][j] = zv;

    const int lbase = (b * N_) * 512;
    for (int ks = 0; ks < 8; ++ks) {
        const int k0 = ks * 64;
        for (int e = tid; e < 3328; e += 256) {
            const int m = e >> 4, kc4 = e & 15;
            float4 fv = make_float4(0.f, 0.f, 0.f, 0.f);
            if (m < N_) fv = *(const float4*)&localf[lbase + m * 512 + k0 + kc4 * 4];
            us4_t pk = {f2bf(fv.x), f2bf(fv.y), f2bf(fv.z), f2bf(fv.w)};
            *(us4_t*)&u.st.A[m * 72 + kc4 * 4] = pk;
        }
        for (int e = tid; e < 1024; e += 256) {
            const int n = e >> 4, kc4 = e & 15;
            float4 fv = make_float4(0.f, 0.f, 0.f, 0.f);
            if (n < ND_) fv = *(const float4*)&text[((size_t)n * C_ + c) * 512 + k0 + kc4 * 4];
            us4_t pk = {f2bf(fv.x), f2bf(fv.y), f2bf(fv.z), f2bf(fv.w)};
            *(us4_t*)&u.st.Bm[n * 72 + kc4 * 4] = pk;
        }
        __syncthreads();
#pragma unroll
        for (int kc = 0; kc < 2; ++kc) {
            short8_t bfr[4];
#pragma unroll
            for (int nt = 0; nt < 4; ++nt)
                bfr[nt] = *(const short8_t*)&u.st.Bm[(nt * 16 + l16) * 72 + kc * 32 + quad * 8];
#pragma unroll
            for (int mi = 0; mi < 4; ++mi) {
                const int mt = w + 4 * mi;
                if (mt < 13) {
                    short8_t af = *(const short8_t*)&u.st.A[(mt * 16 + l16) * 72 + kc * 32 + quad * 8];
#pragma unroll
                    for (int nt = 0; nt < 4; ++nt)
                        acc[mi][nt] = __builtin_amdgcn_mfma_f32_16x16x32_bf16(af, bfr[nt], acc[mi][nt], 0, 0, 0);
                }
            }
        }
        __syncthreads();
    }

#pragma unroll
    for (int mi = 0; mi < 4; ++mi) {
        const int mt = w + 4 * mi;
        if (mt < 13) {
#pragma unroll
            for (int nt = 0; nt < 4; ++nt)
#pragma unroll
                for (int r = 0; r < 4; ++r)
                    u.S[(mt * 16 + quad * 4 + r) * 65 + nt * 16 + l16] = acc[mi][nt][r];
        }
    }
    __syncthreads();

    const float wgv = (lane < 50) ? wgws[b * 50 + lane] : 0.f;
    float waveacc = 0.f;

    for (int j = 0; j < 13; ++j) {
        const int n = w + 4 * j;
        if (n < ND_) {
            float x[4];
#pragma unroll
            for (int i = 0; i < 4; ++i) {
                const int m = lane + 64 * i;
                x[i] = (m < N_) ? u.S[m * 65 + n] : -INFINITY;
            }
#pragma unroll
            for (int k = 2; k <= 64; k <<= 1) {
#pragma unroll
                for (int s2 = k >> 1; s2 > 0; s2 >>= 1) {
                    const bool up = ((lane & k) == 0) == ((lane & s2) == 0);
#pragma unroll
                    for (int r = 0; r < 4; ++r) {
                        const float p = __shfl_xor(x[r], s2);
                        x[r] = up ? fmaxf(x[r], p) : fminf(x[r], p);
                    }
                }
            }
            float m01 = fmaxf(x[0], __shfl_xor(x[1], 63));
            float m23 = fmaxf(x[2], __shfl_xor(x[3], 63));
#pragma unroll
            for (int s2 = 32; s2 > 0; s2 >>= 1) {
                const bool up = (lane & s2) == 0;
                const float p0 = __shfl_xor(m01, s2);
                const float p1 = __shfl_xor(m23, s2);
                m01 = up ? fmaxf(m01, p0) : fminf(m01, p0);
                m23 = up ? fmaxf(m23, p1) : fminf(m23, p1);
            }
            float y = fmaxf(m01, __shfl_xor(m23, 63));
#pragma unroll
            for (int s2 = 32; s2 > 0; s2 >>= 1) {
                const bool up = (lane & s2) == 0;
                const float p = __shfl_xor(y, s2);
                y = up ? fmaxf(y, p) : fminf(y, p);
            }
            float part = (lane < 50) ? y * wgv : 0.f;
#pragma unroll
            for (int off = 32; off; off >>= 1) part += __shfl_xor(part, off);
            waveacc += vws[n * C_ + c] * part;
        }
    }

    if (lane == 0) wavepart[w] = waveacc;
    __syncthreads();
    if (tid == 0)
        out[b * C_ + c] = basev + wavepart[0] + wavepart[1] + wavepart[2] + wavepart[3];
}

extern "C" void kernel_launch(void* const* d_in, const int* in_sizes, int n_in,
                              void* d_out, int out_size, void* d_ws, size_t ws_size,
                              hipStream_t stream) {
    (void)in_sizes; (void)n_in; (void)out_size;
    const float* image = (const float*)d_in[0];
    const float* localf = (const float*)d_in[1];
    const float* text  = (const float*)d_in[2];
    const float* mean  = (const float*)d_in[3];
    float* out = (float*)d_out;

    float* vws   = (float*)d_ws;            // 25500
    float* wgws  = vws + ND_ * C_;          // 1600
    float* s_ws  = wgws + B_ * 50;          // 6272
    float* wm_ws = s_ws + B_ * N_;          // 6272
    const size_t small_bytes = (size_t)(ND_ * C_ + B_ * 50 + 2 * B_ * N_) * 4;
    const size_t bf_bytes = ((size_t)B_ * N_ * D_ + (size_t)ND_ * C_ * D_) * 2;

    hipLaunchKernelGGL(k_v, dim3(C_), dim3(256), 0, stream, mean, text, vws);
    hipLaunchKernelGGL(k_sw, dim3(B_, 7), dim3(256), 0, stream, image, localf, text, s_ws, wm_ws);
    hipLaunchKernelGGL(k_sel, dim3(B_), dim3(64), 0, stream, s_ws, wm_ws, wgws);

    if (ws_size >= small_bytes + bf_bytes) {
        unsigned short* localbf = (unsigned short*)(wm_ws + B_ * N_);
        unsigned short* textbf  = localbf + (size_t)B_ * N_ * D_;
        const int n4_local = B_ * N_ * D_ / 4;
        const int n4_text  = ND_ * C_ * D_ / 4;
        hipLaunchKernelGGL(k_cvt, dim3((n4_local + 255) / 256), dim3(256), 0, stream,
                           (const float4*)localf, (us4_t*)localbf, n4_local);
        hipLaunchKernelGGL(k_cvt, dim3((n4_text + 255) / 256), dim3(256), 0, stream,
                           (const float4*)text, (us4_t*)textbf, n4_text);
        hipLaunchKernelGGL(k_main, dim3(C_, B_), dim3(512), 0, stream,
                           image, mean, localbf, textbf, vws, wgws, out);
    } else {
        hipLaunchKernelGGL(k_main_fb, dim3(C_, B_), dim3(256), 0, stream,
                           image, localf, text, mean, vws, wgws, out);
    }
}